// Round 14
// baseline (734.625 us; speedup 1.0000x reference)
//
#include <hip/hip_runtime.h>

// Correlation: out[b,(p+4)*9+(q+4),y,x] = (1/128) * sum_c A[b,c,y,x]*B[b,c,y+p,x+q]
// A,B = (8,128,128,128) fp32; out = (8,81,128,128) fp32. B zero-padded.
//
// R7 (resubmit x12 — R2..R13 benches died in infra: acquisition timeouts /
// container failures; kernel never ran):
// amortize the per-barrier HBM miss. R5's draining __syncthreads each
// 4-channel chunk exposed ~650cy of A-plane (cold HBM) latency 32x per block;
// R6 proved the drain cannot be removed (it phase-locks y-neighbor blocks so
// L2 absorbs the 9x B reuse: removing it cost +45MB FETCH and regressed).
// So keep the draining barrier, but stage 16 channels (8 f16-packed pairs)
// per body instead of 4: 8 bodies instead of 32, each with ~460cy of dot2
// issue to hide the prefetched miss under. Barriers 33 -> 10 per block.
// Single staging register set: loads for super-chunk k+1 issued at the TOP of
// body k, consumed by the pack+ds_write at the BOTTOM (compiler's counted
// vmcnt wait lands after ~460cy of compute). LDS 35.8KB (4 blocks/CU).
// Keeps R4/R5: f16 pair-packing + v_dot2_f32_f16, 192-thread blocks, grid
// 3072, batch->XCD affinity in low blockIdx bits.

typedef __fp16 h2 __attribute__((ext_vector_type(2)));

#define BW2 144   // padded B row in h2 units; j = x+4, valid j in [0,136), pad to 144

#if __has_builtin(__builtin_amdgcn_fdot2)
  #define FDOT2(a, b, c) __builtin_amdgcn_fdot2((a), (b), (c), false)
#else
  static __device__ inline float FDOT2(h2 a, h2 b, float c) {
      return c + (float)a.x * (float)b.x + (float)a.y * (float)b.y;
  }
#endif

static __device__ inline float pk2f(float lo, float hi) {
    h2 v = __builtin_amdgcn_cvt_pkrtz(lo, hi);   // (f16(lo), f16(hi)) packed
    return __builtin_bit_cast(float, v);
}
static __device__ inline h2 f2h2(float f) { return __builtin_bit_cast(h2, f); }

__global__ __launch_bounds__(192, 3)
void corr_kernel(const float* __restrict__ A, const float* __restrict__ B,
                 float* __restrict__ out)
{
    const int bidx = blockIdx.x;
    const int bb = bidx & 7;          // batch -> XCD affinity
    const int t2 = bidx >> 3;
    const int y  = t2 & 127;
    const int pg = t2 >> 7;           // p-group 0..2

    const int tid  = threadIdx.x;     // 0..191
    const int wave = tid >> 6;        // 0..2
    const int lane = tid & 63;
    const int cs   = lane >> 5;       // pair-select (even/odd pair slot)
    const int x0   = (lane & 31) << 2;
    const int pr   = pg * 3 + wave;   // 0..8 -> p = pr-4

    // 16 channels (8 packed pairs) per buffer
    __shared__ h2 a_s[2][8][128];      // [buf][pair][x]          8 KB
    __shared__ h2 b_s[2][3][8][BW2];   // [buf][row][pair][j]     27.6 KB

    float acc[9][4];
    #pragma unroll
    for (int q = 0; q < 9; ++q)
        #pragma unroll
        for (int i = 0; i < 4; ++i) acc[q][i] = 0.f;

    const long plane = 128L * 128L;
    const float* Abase = A + (long)bb * 128 * plane + (long)y * 128;
    const float* Bbase = B + (long)bb * 128 * plane;

    // ---- staging unit descriptors (computed once) ----
    // B: 3 rows x 8 pairs x 32 col-quads = 768 units; thread t owns u = t+192*i.
    const float* Bu[4]; int Boff[4]; bool Bv[4];
    #pragma unroll
    for (int i = 0; i < 4; ++i) {
        const int u   = tid + 192 * i;
        const int r   = u >> 8;          // row slot 0..2
        const int rem = u & 255;
        const int pru = rem >> 5;        // pair 0..7
        const int col = rem & 31;        // col quad
        const int bys = y + pg * 3 + r - 4;
        Bv[i]  = (unsigned)bys < 128u;
        Bu[i]  = Bbase + (long)(Bv[i] ? bys : 0) * 128 + col * 4
                       + (long)(2 * pru) * plane;
        Boff[i] = (r * 8 + pru) * BW2 + 4 + col * 4;   // h2 index into b_s[buf]
    }
    // A: 8 pairs x 32 col-quads = 256 units; threads 0..127 own u = t, t+128.
    const bool aact = tid < 128;
    const float* Au[2]; int Aoff[2];
    #pragma unroll
    for (int i = 0; i < 2; ++i) {
        const int u   = (tid & 127) + 128 * i;
        const int pru = u >> 5;
        const int col = u & 31;
        Au[i]  = Abase + col * 4 + (long)(2 * pru) * plane;
        Aoff[i] = pru * 128 + col * 4;                 // h2 index into a_s[buf]
    }

    // single staging register set (1 super-chunk in flight)
    float4 rb[4][2], ra[2][2];

#define LOADS(SC) do {                                                   \
    const long choff_ = (long)((SC) << 4) * plane;                       \
    _Pragma("unroll")                                                    \
    for (int i = 0; i < 2; ++i) if (aact) {                              \
        ra[i][0] = *(const float4*)(Au[i] + choff_);                     \
        ra[i][1] = *(const float4*)(Au[i] + choff_ + plane);             \
    }                                                                    \
    _Pragma("unroll")                                                    \
    for (int i = 0; i < 4; ++i) if (Bv[i]) {                             \
        rb[i][0] = *(const float4*)(Bu[i] + choff_);                     \
        rb[i][1] = *(const float4*)(Bu[i] + choff_ + plane);             \
    }                                                                    \
} while (0)

#define STAGES(BUF) do {                                                 \
    h2* bb_ = &b_s[(BUF)][0][0][0];                                      \
    _Pragma("unroll")                                                    \
    for (int i = 0; i < 4; ++i) if (Bv[i]) {                             \
        float4 w_;                                                       \
        w_.x = pk2f(rb[i][0].x, rb[i][1].x);                             \
        w_.y = pk2f(rb[i][0].y, rb[i][1].y);                             \
        w_.z = pk2f(rb[i][0].z, rb[i][1].z);                             \
        w_.w = pk2f(rb[i][0].w, rb[i][1].w);                             \
        *(float4*)(bb_ + Boff[i]) = w_;                                  \
    }                                                                    \
    if (aact) {                                                          \
        h2* aa_ = &a_s[(BUF)][0][0];                                     \
        _Pragma("unroll")                                                \
        for (int i = 0; i < 2; ++i) {                                    \
            float4 w_;                                                   \
            w_.x = pk2f(ra[i][0].x, ra[i][1].x);                         \
            w_.y = pk2f(ra[i][0].y, ra[i][1].y);                         \
            w_.z = pk2f(ra[i][0].z, ra[i][1].z);                         \
            w_.w = pk2f(ra[i][0].w, ra[i][1].w);                         \
            *(float4*)(aa_ + Aoff[i]) = w_;                              \
        }                                                                \
    }                                                                    \
} while (0)

#define COMPUTE(BUF) do {                                                        \
    _Pragma("unroll")                                                            \
    for (int pp = 0; pp < 4; ++pp) {                                             \
        const int pair_ = (pp << 1) | cs;                                        \
        const float4 av  = *(const float4*)&a_s[(BUF)][pair_][x0];               \
        const float4 b0v = *(const float4*)&b_s[(BUF)][wave][pair_][x0];         \
        const float4 b1v = *(const float4*)&b_s[(BUF)][wave][pair_][x0 + 4];     \
        const float4 b2v = *(const float4*)&b_s[(BUF)][wave][pair_][x0 + 8];     \
        const h2 a2[4] = { f2h2(av.x), f2h2(av.y), f2h2(av.z), f2h2(av.w) };     \
        const h2 w[12] = { f2h2(b0v.x), f2h2(b0v.y), f2h2(b0v.z), f2h2(b0v.w),   \
                           f2h2(b1v.x), f2h2(b1v.y), f2h2(b1v.z), f2h2(b1v.w),   \
                           f2h2(b2v.x), f2h2(b2v.y), f2h2(b2v.z), f2h2(b2v.w) }; \
        _Pragma("unroll")                                                        \
        for (int q = 0; q < 9; ++q)                                              \
            _Pragma("unroll")                                                    \
            for (int i = 0; i < 4; ++i)                                          \
                acc[q][i] = FDOT2(a2[i], w[q + i], acc[q][i]);                   \
    }                                                                            \
} while (0)

    // prologue: issue super-chunk 0 loads, zero LDS pads under their latency
    LOADS(0);
    {
        float4* pa = (float4*)&a_s[0][0][0];
        const int na = 2 * 8 * 128 / 4;          // 512 float4
        for (int i = tid; i < na; i += 192) pa[i] = make_float4(0.f, 0.f, 0.f, 0.f);
        float4* pb = (float4*)&b_s[0][0][0][0];
        const int nb = 2 * 3 * 8 * BW2 / 4;      // 1728 float4
        for (int i = tid; i < nb; i += 192) pb[i] = make_float4(0.f, 0.f, 0.f, 0.f);
    }
    __syncthreads();        // zero-init visible
    STAGES(0);
    __syncthreads();        // buf0 ready

    // 8 super-chunks of 16 channels
    #pragma unroll
    for (int k = 0; k < 7; ++k) {
        LOADS(k + 1);           // prefetch next super-chunk (consumed at STAGES)
        COMPUTE(k & 1);         // ~460cy of dot2 issue hides the load latency
        STAGES((k + 1) & 1);    // counted vmcnt wait lands here
        __syncthreads();        // drain + phase-lock (keeps B L2-reuse intact)
    }
    COMPUTE(1);                 // k = 7

#undef COMPUTE
#undef STAGES
#undef LOADS

    // combine pair-split halves (lane L += lane L+32)
    #pragma unroll
    for (int q = 0; q < 9; ++q)
        #pragma unroll
        for (int i = 0; i < 4; ++i)
            acc[q][i] += __shfl_down(acc[q][i], 32);

    if (cs == 0) {
        const float scale = 1.0f / 128.0f;
        float* obase = out + (((long)bb * 81 + (long)pr * 9) * 128 + y) * 128 + x0;
        #pragma unroll
        for (int q = 0; q < 9; ++q) {
            const float4 v = make_float4(acc[q][0] * scale, acc[q][1] * scale,
                                         acc[q][2] * scale, acc[q][3] * scale);
            *(float4*)(obase + (long)q * plane) = v;
        }
    }
}

extern "C" void kernel_launch(void* const* d_in, const int* in_sizes, int n_in,
                              void* d_out, int out_size, void* d_ws, size_t ws_size,
                              hipStream_t stream) {
    const float* a = (const float*)d_in[0];
    const float* b = (const float*)d_in[1];
    float* out = (float*)d_out;
    // grid: 8 batches * 128 y * 3 p-groups = 3072 blocks; 192 threads (3 waves)
    hipLaunchKernelGGL(corr_kernel, dim3(3072), dim3(192), 0, stream, a, b, out);
}

// Round 15
// 550.649 us; speedup vs baseline: 1.3341x; 1.3341x over previous
//
#include <hip/hip_runtime.h>

// Correlation: out[b,(p+4)*9+(q+4),y,x] = (1/128) * sum_c A[b,c,y,x]*B[b,c,y+p,x+q]
// A,B = (8,128,128,128) fp32; out = (8,81,128,128) fp32. B zero-padded.
//
// R8: fix R7's scratch spill. R7 (16-ch superchunks) needed ~200 VGPR for its
// 24-float4 staging set; __launch_bounds__(192,3) caps ~170 -> compiler
// spilled staging to scratch (VGPR=84, WRITE_SIZE 41MB->1.37GB, dur 650us).
// R8 halves the superchunk to 8 channels (4 f16-packed pairs): staging set =
// 6 float4 (24 VGPR), total pressure ~110-125 -> no spill. Still 2x R5's
// amortization: 16 bodies instead of 32, ~220cy dot2 issue per body to hide
// the prefetched A-plane miss; barriers 33 -> 18. Draining __syncthreads kept
// (R6: removing it breaks y-neighbor phase-lock, +45MB FETCH). LDS 17.5KB.
// Keeps f16 pair-packing + v_dot2_f32_f16, 192-thread blocks, grid 3072,
// batch->XCD affinity in low blockIdx bits.

typedef __fp16 h2 __attribute__((ext_vector_type(2)));

#define BW2 144   // padded B row in h2 units; j = x+4, valid j in [0,136), pad to 144

#if __has_builtin(__builtin_amdgcn_fdot2)
  #define FDOT2(a, b, c) __builtin_amdgcn_fdot2((a), (b), (c), false)
#else
  static __device__ inline float FDOT2(h2 a, h2 b, float c) {
      return c + (float)a.x * (float)b.x + (float)a.y * (float)b.y;
  }
#endif

static __device__ inline float pk2f(float lo, float hi) {
    h2 v = __builtin_amdgcn_cvt_pkrtz(lo, hi);   // (f16(lo), f16(hi)) packed
    return __builtin_bit_cast(float, v);
}
static __device__ inline h2 f2h2(float f) { return __builtin_bit_cast(h2, f); }

__global__ __launch_bounds__(192, 3)
void corr_kernel(const float* __restrict__ A, const float* __restrict__ B,
                 float* __restrict__ out)
{
    const int bidx = blockIdx.x;
    const int bb = bidx & 7;          // batch -> XCD affinity
    const int t2 = bidx >> 3;
    const int y  = t2 & 127;
    const int pg = t2 >> 7;           // p-group 0..2

    const int tid  = threadIdx.x;     // 0..191
    const int wave = tid >> 6;        // 0..2
    const int lane = tid & 63;
    const int cs   = lane >> 5;       // pair-select (even/odd pair slot)
    const int x0   = (lane & 31) << 2;
    const int pr   = pg * 3 + wave;   // 0..8 -> p = pr-4

    // 8 channels (4 packed pairs) per buffer
    __shared__ h2 a_s[2][4][128];      // [buf][pair][x]          4 KB
    __shared__ h2 b_s[2][3][4][BW2];   // [buf][row][pair][j]     13.5 KB

    float acc[9][4];
    #pragma unroll
    for (int q = 0; q < 9; ++q)
        #pragma unroll
        for (int i = 0; i < 4; ++i) acc[q][i] = 0.f;

    const long plane = 128L * 128L;
    const float* Abase = A + (long)bb * 128 * plane + (long)y * 128;
    const float* Bbase = B + (long)bb * 128 * plane;

    // ---- staging unit descriptors (computed once) ----
    // B: 3 rows x 4 pairs x 32 col-quads = 384 units; thread t owns u = t+192*i.
    const float* Bu[2]; int Boff[2]; bool Bv[2];
    #pragma unroll
    for (int i = 0; i < 2; ++i) {
        const int u   = tid + 192 * i;
        const int r   = u >> 7;          // row slot 0..2
        const int rem = u & 127;
        const int pru = rem >> 5;        // pair 0..3
        const int col = rem & 31;        // col quad
        const int bys = y + pg * 3 + r - 4;
        Bv[i]  = (unsigned)bys < 128u;
        Bu[i]  = Bbase + (long)(Bv[i] ? bys : 0) * 128 + col * 4
                       + (long)(2 * pru) * plane;
        Boff[i] = (r * 4 + pru) * BW2 + 4 + col * 4;   // h2 index into b_s[buf]
    }
    // A: 4 pairs x 32 col-quads = 128 units; threads 0..127 own u = tid.
    const bool aact = tid < 128;
    const int apru = (tid & 127) >> 5;
    const int acol = tid & 31;
    const float* Au = Abase + acol * 4 + (long)(2 * apru) * plane;
    const int Aoff = apru * 128 + acol * 4;            // h2 index into a_s[buf]

    // single staging register set: 6 float4 = 24 VGPR (R7's 24 f4 spilled)
    float4 rb[2][2], ra[2];

#define LOADS(SC) do {                                                   \
    const long choff_ = (long)((SC) << 3) * plane;                       \
    if (aact) {                                                          \
        ra[0] = *(const float4*)(Au + choff_);                           \
        ra[1] = *(const float4*)(Au + choff_ + plane);                   \
    }                                                                    \
    _Pragma("unroll")                                                    \
    for (int i = 0; i < 2; ++i) if (Bv[i]) {                             \
        rb[i][0] = *(const float4*)(Bu[i] + choff_);                     \
        rb[i][1] = *(const float4*)(Bu[i] + choff_ + plane);             \
    }                                                                    \
} while (0)

#define STAGES(BUF) do {                                                 \
    h2* bb_ = &b_s[(BUF)][0][0][0];                                      \
    _Pragma("unroll")                                                    \
    for (int i = 0; i < 2; ++i) if (Bv[i]) {                             \
        float4 w_;                                                       \
        w_.x = pk2f(rb[i][0].x, rb[i][1].x);                             \
        w_.y = pk2f(rb[i][0].y, rb[i][1].y);                             \
        w_.z = pk2f(rb[i][0].z, rb[i][1].z);                             \
        w_.w = pk2f(rb[i][0].w, rb[i][1].w);                             \
        *(float4*)(bb_ + Boff[i]) = w_;                                  \
    }                                                                    \
    if (aact) {                                                          \
        float4 w_;                                                       \
        w_.x = pk2f(ra[0].x, ra[1].x);                                   \
        w_.y = pk2f(ra[0].y, ra[1].y);                                   \
        w_.z = pk2f(ra[0].z, ra[1].z);                                   \
        w_.w = pk2f(ra[0].w, ra[1].w);                                   \
        *(float4*)(&a_s[(BUF)][0][0] + Aoff) = w_;                       \
    }                                                                    \
} while (0)

#define COMPUTE(BUF) do {                                                        \
    _Pragma("unroll")                                                            \
    for (int pp = 0; pp < 2; ++pp) {                                             \
        const int pair_ = (pp << 1) | cs;                                        \
        const float4 av  = *(const float4*)&a_s[(BUF)][pair_][x0];               \
        const float4 b0v = *(const float4*)&b_s[(BUF)][wave][pair_][x0];         \
        const float4 b1v = *(const float4*)&b_s[(BUF)][wave][pair_][x0 + 4];     \
        const float4 b2v = *(const float4*)&b_s[(BUF)][wave][pair_][x0 + 8];     \
        const h2 a2[4] = { f2h2(av.x), f2h2(av.y), f2h2(av.z), f2h2(av.w) };     \
        const h2 w[12] = { f2h2(b0v.x), f2h2(b0v.y), f2h2(b0v.z), f2h2(b0v.w),   \
                           f2h2(b1v.x), f2h2(b1v.y), f2h2(b1v.z), f2h2(b1v.w),   \
                           f2h2(b2v.x), f2h2(b2v.y), f2h2(b2v.z), f2h2(b2v.w) }; \
        _Pragma("unroll")                                                        \
        for (int q = 0; q < 9; ++q)                                              \
            _Pragma("unroll")                                                    \
            for (int i = 0; i < 4; ++i)                                          \
                acc[q][i] = FDOT2(a2[i], w[q + i], acc[q][i]);                   \
    }                                                                            \
} while (0)

    // prologue: issue super-chunk 0 loads, zero LDS pads under their latency
    LOADS(0);
    {
        float4* pa = (float4*)&a_s[0][0][0];
        const int na = 2 * 4 * 128 / 4;          // 256 float4
        for (int i = tid; i < na; i += 192) pa[i] = make_float4(0.f, 0.f, 0.f, 0.f);
        float4* pb = (float4*)&b_s[0][0][0][0];
        const int nb = 2 * 3 * 4 * BW2 / 4;      // 864 float4
        for (int i = tid; i < nb; i += 192) pb[i] = make_float4(0.f, 0.f, 0.f, 0.f);
    }
    __syncthreads();        // zero-init visible
    STAGES(0);
    __syncthreads();        // buf0 ready

    // 16 super-chunks of 8 channels
    #pragma unroll
    for (int k = 0; k < 15; ++k) {
        LOADS(k + 1);           // prefetch next super-chunk (consumed at STAGES)
        COMPUTE(k & 1);         // ~220cy of dot2 issue hides the load latency
        STAGES((k + 1) & 1);    // counted vmcnt wait lands here
        __syncthreads();        // drain + phase-lock (keeps B L2-reuse intact)
    }
    COMPUTE(1);                 // k = 15

#undef COMPUTE
#undef STAGES
#undef LOADS

    // combine pair-split halves (lane L += lane L+32)
    #pragma unroll
    for (int q = 0; q < 9; ++q)
        #pragma unroll
        for (int i = 0; i < 4; ++i)
            acc[q][i] += __shfl_down(acc[q][i], 32);

    if (cs == 0) {
        const float scale = 1.0f / 128.0f;
        float* obase = out + (((long)bb * 81 + (long)pr * 9) * 128 + y) * 128 + x0;
        #pragma unroll
        for (int q = 0; q < 9; ++q) {
            const float4 v = make_float4(acc[q][0] * scale, acc[q][1] * scale,
                                         acc[q][2] * scale, acc[q][3] * scale);
            *(float4*)(obase + (long)q * plane) = v;
        }
    }
}

extern "C" void kernel_launch(void* const* d_in, const int* in_sizes, int n_in,
                              void* d_out, int out_size, void* d_ws, size_t ws_size,
                              hipStream_t stream) {
    const float* a = (const float*)d_in[0];
    const float* b = (const float*)d_in[1];
    float* out = (float*)d_out;
    // grid: 8 batches * 128 y * 3 p-groups = 3072 blocks; 192 threads (3 waves)
    hipLaunchKernelGGL(corr_kernel, dim3(3072), dim3(192), 0, stream, a, b, out);
}

// Round 16
// 203.923 us; speedup vs baseline: 3.6025x; 2.7003x over previous
//
#include <hip/hip_runtime.h>

// Correlation: out[b,(p+4)*9+(q+4),y,x] = (1/128) * sum_c A[b,c,y,x]*B[b,c,y+p,x+q]
// A,B = (8,128,128,128) fp32; out = (8,81,128,128) fp32. B zero-padded.
//
// R9: kill the k-loop unroll. R7/R8 both spilled staging to scratch with the
// SAME VGPR=84 fingerprint despite a 4x difference in staging-set size
// (24 f4 vs 6 f4) -> the spill is caused by `#pragma unroll` on the main
// loop (full unroll lets the scheduler hoist many superchunks' LOADS above
// their STAGES, pressure explodes, allocator spills staging). R5/R6 with
// runtime loops were clean (VGPR 40/60). R9 = R8 geometry (8-channel
// superchunks, 16 bodies, 2x R5's per-barrier amortization) with
// `#pragma clang loop unroll(disable)` on the k-loop. One staging set in
// flight by construction: LOADS(k+1) -> ~220cy COMPUTE issue -> counted
// vmcnt at STAGES -> draining __syncthreads (phase-lock for B L2-reuse, R6).
// LDS 17.5KB. f16 pair-packing + v_dot2_f32_f16, 192 threads, grid 3072,
// batch->XCD affinity in low blockIdx bits.

typedef __fp16 h2 __attribute__((ext_vector_type(2)));

#define BW2 144   // padded B row in h2 units; j = x+4, valid j in [0,136), pad to 144

#if __has_builtin(__builtin_amdgcn_fdot2)
  #define FDOT2(a, b, c) __builtin_amdgcn_fdot2((a), (b), (c), false)
#else
  static __device__ inline float FDOT2(h2 a, h2 b, float c) {
      return c + (float)a.x * (float)b.x + (float)a.y * (float)b.y;
  }
#endif

static __device__ inline float pk2f(float lo, float hi) {
    h2 v = __builtin_amdgcn_cvt_pkrtz(lo, hi);   // (f16(lo), f16(hi)) packed
    return __builtin_bit_cast(float, v);
}
static __device__ inline h2 f2h2(float f) { return __builtin_bit_cast(h2, f); }

__global__ __launch_bounds__(192, 3)
void corr_kernel(const float* __restrict__ A, const float* __restrict__ B,
                 float* __restrict__ out)
{
    const int bidx = blockIdx.x;
    const int bb = bidx & 7;          // batch -> XCD affinity
    const int t2 = bidx >> 3;
    const int y  = t2 & 127;
    const int pg = t2 >> 7;           // p-group 0..2

    const int tid  = threadIdx.x;     // 0..191
    const int wave = tid >> 6;        // 0..2
    const int lane = tid & 63;
    const int cs   = lane >> 5;       // pair-select (even/odd pair slot)
    const int x0   = (lane & 31) << 2;
    const int pr   = pg * 3 + wave;   // 0..8 -> p = pr-4

    // 8 channels (4 packed pairs) per buffer
    __shared__ h2 a_s[2][4][128];      // [buf][pair][x]          4 KB
    __shared__ h2 b_s[2][3][4][BW2];   // [buf][row][pair][j]     13.5 KB

    float acc[9][4];
    #pragma unroll
    for (int q = 0; q < 9; ++q)
        #pragma unroll
        for (int i = 0; i < 4; ++i) acc[q][i] = 0.f;

    const long plane = 128L * 128L;
    const float* Abase = A + (long)bb * 128 * plane + (long)y * 128;
    const float* Bbase = B + (long)bb * 128 * plane;

    // ---- staging unit descriptors (computed once) ----
    // B: 3 rows x 4 pairs x 32 col-quads = 384 units; thread t owns u = t+192*i.
    const float* Bu[2]; int Boff[2]; bool Bv[2];
    #pragma unroll
    for (int i = 0; i < 2; ++i) {
        const int u   = tid + 192 * i;
        const int r   = u >> 7;          // row slot 0..2
        const int rem = u & 127;
        const int pru = rem >> 5;        // pair 0..3
        const int col = rem & 31;        // col quad
        const int bys = y + pg * 3 + r - 4;
        Bv[i]  = (unsigned)bys < 128u;
        Bu[i]  = Bbase + (long)(Bv[i] ? bys : 0) * 128 + col * 4
                       + (long)(2 * pru) * plane;
        Boff[i] = (r * 4 + pru) * BW2 + 4 + col * 4;   // h2 index into b_s[buf]
    }
    // A: 4 pairs x 32 col-quads = 128 units; threads 0..127 own u = tid.
    const bool aact = tid < 128;
    const int apru = (tid & 127) >> 5;
    const int acol = tid & 31;
    const float* Au = Abase + acol * 4 + (long)(2 * apru) * plane;
    const int Aoff = apru * 128 + acol * 4;            // h2 index into a_s[buf]

    // single staging register set: 6 float4 = 24 VGPR
    float4 rb[2][2], ra[2];

#define LOADS(SC) do {                                                   \
    const long choff_ = (long)((SC) << 3) * plane;                       \
    if (aact) {                                                          \
        ra[0] = *(const float4*)(Au + choff_);                           \
        ra[1] = *(const float4*)(Au + choff_ + plane);                   \
    }                                                                    \
    _Pragma("unroll")                                                    \
    for (int i = 0; i < 2; ++i) if (Bv[i]) {                             \
        rb[i][0] = *(const float4*)(Bu[i] + choff_);                     \
        rb[i][1] = *(const float4*)(Bu[i] + choff_ + plane);             \
    }                                                                    \
} while (0)

#define STAGES(BUF) do {                                                 \
    h2* bb_ = &b_s[(BUF)][0][0][0];                                      \
    _Pragma("unroll")                                                    \
    for (int i = 0; i < 2; ++i) if (Bv[i]) {                             \
        float4 w_;                                                       \
        w_.x = pk2f(rb[i][0].x, rb[i][1].x);                             \
        w_.y = pk2f(rb[i][0].y, rb[i][1].y);                             \
        w_.z = pk2f(rb[i][0].z, rb[i][1].z);                             \
        w_.w = pk2f(rb[i][0].w, rb[i][1].w);                             \
        *(float4*)(bb_ + Boff[i]) = w_;                                  \
    }                                                                    \
    if (aact) {                                                          \
        float4 w_;                                                       \
        w_.x = pk2f(ra[0].x, ra[1].x);                                   \
        w_.y = pk2f(ra[0].y, ra[1].y);                                   \
        w_.z = pk2f(ra[0].z, ra[1].z);                                   \
        w_.w = pk2f(ra[0].w, ra[1].w);                                   \
        *(float4*)(&a_s[(BUF)][0][0] + Aoff) = w_;                       \
    }                                                                    \
} while (0)

#define COMPUTE(BUF) do {                                                        \
    _Pragma("unroll")                                                            \
    for (int pp = 0; pp < 2; ++pp) {                                             \
        const int pair_ = (pp << 1) | cs;                                        \
        const float4 av  = *(const float4*)&a_s[(BUF)][pair_][x0];               \
        const float4 b0v = *(const float4*)&b_s[(BUF)][wave][pair_][x0];         \
        const float4 b1v = *(const float4*)&b_s[(BUF)][wave][pair_][x0 + 4];     \
        const float4 b2v = *(const float4*)&b_s[(BUF)][wave][pair_][x0 + 8];     \
        const h2 a2[4] = { f2h2(av.x), f2h2(av.y), f2h2(av.z), f2h2(av.w) };     \
        const h2 w[12] = { f2h2(b0v.x), f2h2(b0v.y), f2h2(b0v.z), f2h2(b0v.w),   \
                           f2h2(b1v.x), f2h2(b1v.y), f2h2(b1v.z), f2h2(b1v.w),   \
                           f2h2(b2v.x), f2h2(b2v.y), f2h2(b2v.z), f2h2(b2v.w) }; \
        _Pragma("unroll")                                                        \
        for (int q = 0; q < 9; ++q)                                              \
            _Pragma("unroll")                                                    \
            for (int i = 0; i < 4; ++i)                                          \
                acc[q][i] = FDOT2(a2[i], w[q + i], acc[q][i]);                   \
    }                                                                            \
} while (0)

    // prologue: issue super-chunk 0 loads, zero LDS pads under their latency
    LOADS(0);
    {
        float4* pa = (float4*)&a_s[0][0][0];
        const int na = 2 * 4 * 128 / 4;          // 256 float4
        for (int i = tid; i < na; i += 192) pa[i] = make_float4(0.f, 0.f, 0.f, 0.f);
        float4* pb = (float4*)&b_s[0][0][0][0];
        const int nb = 2 * 3 * 4 * BW2 / 4;      // 864 float4
        for (int i = tid; i < nb; i += 192) pb[i] = make_float4(0.f, 0.f, 0.f, 0.f);
    }
    __syncthreads();        // zero-init visible
    STAGES(0);
    __syncthreads();        // buf0 ready

    // 16 super-chunks of 8 channels — RUNTIME loop (full unroll caused the
    // R7/R8 scratch spill: scheduler hoisted many superchunks' loads, VGPR
    // pressure exploded past the 170 cap, staging went to scratch)
    #pragma clang loop unroll(disable)
    for (int k = 0; k < 15; ++k) {
        const int buf = k & 1;
        LOADS(k + 1);           // prefetch next super-chunk (consumed at STAGES)
        COMPUTE(buf);           // ~220cy of dot2 issue hides the load latency
        STAGES(buf ^ 1);        // counted vmcnt wait lands here
        __syncthreads();        // drain + phase-lock (keeps B L2-reuse intact)
    }
    COMPUTE(1);                 // k = 15

#undef COMPUTE
#undef STAGES
#undef LOADS

    // combine pair-split halves (lane L += lane L+32)
    #pragma unroll
    for (int q = 0; q < 9; ++q)
        #pragma unroll
        for (int i = 0; i < 4; ++i)
            acc[q][i] += __shfl_down(acc[q][i], 32);

    if (cs == 0) {
        const float scale = 1.0f / 128.0f;
        float* obase = out + (((long)bb * 81 + (long)pr * 9) * 128 + y) * 128 + x0;
        #pragma unroll
        for (int q = 0; q < 9; ++q) {
            const float4 v = make_float4(acc[q][0] * scale, acc[q][1] * scale,
                                         acc[q][2] * scale, acc[q][3] * scale);
            *(float4*)(obase + (long)q * plane) = v;
        }
    }
}

extern "C" void kernel_launch(void* const* d_in, const int* in_sizes, int n_in,
                              void* d_out, int out_size, void* d_ws, size_t ws_size,
                              hipStream_t stream) {
    const float* a = (const float*)d_in[0];
    const float* b = (const float*)d_in[1];
    float* out = (float*)d_out;
    // grid: 8 batches * 128 y * 3 p-groups = 3072 blocks; 192 threads (3 waves)
    hipLaunchKernelGGL(corr_kernel, dim3(3072), dim3(192), 0, stream, a, b, out);
}